// Round 3
// baseline (296.837 us; speedup 1.0000x reference)
//
#include <hip/hip_runtime.h>

// B=4096, L=64, D=128, counts in [0,64].
#define DD   128
#define LLEN 64
#define TMAX 65                  // table rows: count values 0..64
#define ROWS_PER_BLK 4           // one wave (64 lanes) per batch row
#define TAB4 (TMAX * (DD / 4))   // 2080 float4 = 33280 B (fits L1/L2)

typedef __attribute__((ext_vector_type(4))) float f32x4;

// Kernel 1: tab[a][e] = b2[e] + sum_d relu(a*W1[d]+b1[d]) * W2[d][e]
// (b2 folded in: out = tab[A0] + tab[A1] gives ... + 2*b2 as required)
__global__ void build_table_kernel(const float* __restrict__ W1,
                                   const float* __restrict__ b1,
                                   const float* __restrict__ W2,
                                   const float* __restrict__ b2,
                                   float* __restrict__ tab) {
    const int a = blockIdx.x;    // 0..64
    const int e = threadIdx.x;   // 0..127
    const float fa = (float)a;
    float acc = b2[e];
#pragma unroll 8
    for (int d = 0; d < DD; ++d) {
        float h = fmaxf(fmaf(fa, W1[d], b1[d]), 0.f);
        acc = fmaf(h, W2[d * DD + e], acc);
    }
    tab[a * DD + e] = acc;
}

// Kernel 2: ZERO LDS, no barriers. The 33 KB table is read directly through
// the vector-cache path (L1 32 KB, shared 33 KB table -> near-100% L1/L2 hit
// after warmup). No LDS -> occupancy capped only by VGPR: launch_bounds(256,8)
// targets 8 blocks/CU = 32 waves/CU, 2x the LDS-table variants, with no
// staging prologue or block-end drain bubbles at large block granularity.
__global__ __launch_bounds__(256, 8) void nif_main_kernel(
    const int* __restrict__ src_id, const int* __restrict__ dst_id,
    const int* __restrict__ src_nb, const int* __restrict__ dst_nb,
    const float* __restrict__ tab, float* __restrict__ out, int B) {
    const int tid  = threadIdx.x;
    const int lane = tid & 63;
    const int w    = tid >> 6;                       // wave id 0..3
    const int b    = blockIdx.x * ROWS_PER_BLK + w;  // this wave's batch row

    const int vs  = src_nb[(size_t)b * LLEN + lane];
    const int vd  = dst_nb[(size_t)b * LLEN + lane];
    const int sid = src_id[b];
    const int did = dst_id[b];

    // All-pairs counts, register-only (uniform shuffle index -> readlane).
    int c_src = 0, c_dos = 0, c_dst = 0, c_sod = 0;
#pragma unroll 8
    for (int j = 0; j < LLEN; ++j) {
        const int sj = __shfl(vs, j);
        const int dj = __shfl(vd, j);
        c_src += (sj == vs);   // count of S[i] in S
        c_dos += (dj == vs);   // count of S[i] in D
        c_dst += (dj == vd);   // count of D[i] in D
        c_sod += (sj == vd);   // count of D[i] in S
    }
    const int cd_sid = __popcll(__ballot(vd == sid));  // count of sid in D-row
    const int cs_did = __popcll(__ballot(vs == did));  // count of did in S-row
    const bool s_in_d = (cd_sid > 0);
    const bool same   = (sid == did);
    const bool c2     = (cs_did > 0) || (same && s_in_d);
    const int  v2     = (same && s_in_d) ? cd_sid : cs_did;
    // lane l of this wave holds the 4 table indices for output row l:
    const int A0 = c_src;                                  // src_app[...,0]
    const int A1 = (vs == did && c2) ? v2 : c_dos;         // src_app[...,1]
    const int C0 = (vd == sid && s_in_d) ? cd_sid : c_sod; // dst_app[...,0]
    const int C1 = c_dst;                                  // dst_app[...,1]

    // Store loop: per iteration, this wave emits rows 2k (lanes 0-31) and
    // 2k+1 (lanes 32-63) of src — one CONTIGUOUS 1 KiB store — then the
    // same two rows of dst. Table rows read straight from L1/L2; each
    // global_load_dwordx4 covers two dense 512 B row segments.
    const f32x4* __restrict__ tab4 = (const f32x4*)tab;
    const int e4 = lane & 31;        // float4 column 0..31
    const int lh = lane >> 5;        // which of the two L-rows this half handles
    f32x4* __restrict__ out4 = (f32x4*)out;
    const size_t src_base = (size_t)b * (LLEN * DD / 4);   // f32x4 units
    const size_t dst_base = src_base + (size_t)B * (LLEN * DD / 4);

#pragma unroll 4
    for (int k = 0; k < 32; ++k) {
        const int l = 2 * k + lh;          // L-row 0..63
        const size_t idx4 = (size_t)l * 32 + e4;
        const int a0p = __shfl(A0, 2 * k), a0q = __shfl(A0, 2 * k + 1);
        const int a1p = __shfl(A1, 2 * k), a1q = __shfl(A1, 2 * k + 1);
        const int c0p = __shfl(C0, 2 * k), c0q = __shfl(C0, 2 * k + 1);
        const int c1p = __shfl(C1, 2 * k), c1q = __shfl(C1, 2 * k + 1);
        const int a0 = lh ? a0q : a0p;
        const int a1 = lh ? a1q : a1p;
        const int c0 = lh ? c0q : c0p;
        const int c1 = lh ? c1q : c1p;
        const f32x4 t = tab4[a0 * 32 + e4] + tab4[a1 * 32 + e4];
        out4[src_base + idx4] = t;
        const f32x4 u = tab4[c0 * 32 + e4] + tab4[c1 * 32 + e4];
        out4[dst_base + idx4] = u;
    }
}

extern "C" void kernel_launch(void* const* d_in, const int* in_sizes, int n_in,
                              void* d_out, int out_size, void* d_ws, size_t ws_size,
                              hipStream_t stream) {
    const int*   src_id = (const int*)d_in[0];
    const int*   dst_id = (const int*)d_in[1];
    const int*   src_nb = (const int*)d_in[2];
    const int*   dst_nb = (const int*)d_in[3];
    const float* W1     = (const float*)d_in[4];
    const float* b1     = (const float*)d_in[5];
    const float* W2     = (const float*)d_in[6];
    const float* b2     = (const float*)d_in[7];
    float*       out    = (float*)d_out;
    float*       tab    = (float*)d_ws;   // 65*128 fp32 = 33280 B scratch

    const int B = in_sizes[0];

    build_table_kernel<<<TMAX, DD, 0, stream>>>(W1, b1, W2, b2, tab);
    nif_main_kernel<<<B / ROWS_PER_BLK, 256, 0, stream>>>(
        src_id, dst_id, src_nb, dst_nb, tab, out, B);
}

// Round 4
// 295.451 us; speedup vs baseline: 1.0047x; 1.0047x over previous
//
#include <hip/hip_runtime.h>

// B=4096, L=64, D=128, counts in [0,64].
#define DD   128
#define LLEN 64
#define TMAX 65                  // table rows: count values 0..64
#define TAB4 (TMAX * (DD / 4))   // 2080 float4 = 33280 B

typedef __attribute__((ext_vector_type(4))) float f32x4;

// Kernel 1: tab[a][e] = b2[e] + sum_d relu(a*W1[d]+b1[d]) * W2[d][e]
// (b2 folded in: out = tab[A0] + tab[A1] gives ... + 2*b2 as required)
__global__ void build_table_kernel(const float* __restrict__ W1,
                                   const float* __restrict__ b1,
                                   const float* __restrict__ W2,
                                   const float* __restrict__ b2,
                                   float* __restrict__ tab) {
    const int a = blockIdx.x;    // 0..64
    const int e = threadIdx.x;   // 0..127
    const float fa = (float)a;
    float acc = b2[e];
#pragma unroll 8
    for (int d = 0; d < DD; ++d) {
        float h = fmaxf(fmaf(fa, W1[d], b1[d]), 0.f);
        acc = fmaf(h, W2[d * DD + e], acc);
    }
    tab[a * DD + e] = acc;
}

// Kernel 2: counts phase only. One wave per batch row; packs the four table
// indices for output row (b,l) into one u32 of IDX (1 MB, L2/L3-resident).
__global__ __launch_bounds__(256) void build_index_kernel(
    const int* __restrict__ src_id, const int* __restrict__ dst_id,
    const int* __restrict__ src_nb, const int* __restrict__ dst_nb,
    unsigned* __restrict__ IDX, int B) {
    const int tid  = threadIdx.x;
    const int lane = tid & 63;
    const int w    = tid >> 6;                 // wave id 0..3
    const int b    = blockIdx.x * 4 + w;       // this wave's batch row

    const int vs  = src_nb[(size_t)b * LLEN + lane];
    const int vd  = dst_nb[(size_t)b * LLEN + lane];
    const int sid = src_id[b];
    const int did = dst_id[b];

    int c_src = 0, c_dos = 0, c_dst = 0, c_sod = 0;
#pragma unroll 8
    for (int j = 0; j < LLEN; ++j) {
        const int sj = __shfl(vs, j);
        const int dj = __shfl(vd, j);
        c_src += (sj == vs);   // count of S[i] in S
        c_dos += (dj == vs);   // count of S[i] in D
        c_dst += (dj == vd);   // count of D[i] in D
        c_sod += (sj == vd);   // count of D[i] in S
    }
    const int cd_sid = __popcll(__ballot(vd == sid));  // count of sid in D-row
    const int cs_did = __popcll(__ballot(vs == did));  // count of did in S-row
    const bool s_in_d = (cd_sid > 0);
    const bool same   = (sid == did);
    const bool c2     = (cs_did > 0) || (same && s_in_d);
    const int  v2     = (same && s_in_d) ? cd_sid : cs_did;
    const unsigned A0 = c_src;                                  // src_app[...,0]
    const unsigned A1 = (vs == did && c2) ? v2 : c_dos;         // src_app[...,1]
    const unsigned C0 = (vd == sid && s_in_d) ? cd_sid : c_sod; // dst_app[...,0]
    const unsigned C1 = c_dst;                                  // dst_app[...,1]

    IDX[(size_t)b * LLEN + lane] = A0 | (A1 << 8) | (C0 << 16) | (C1 << 24);
}

// Kernel 3: the store stream — an exact fillBuffer clone. Grid-stride over
// contiguous 1 KiB chunks of the output in LINEAR ADDRESS ORDER, so the whole
// chip advances one contiguous write front (the pattern that measures
// 6.5 TB/s), instead of 8192 scattered per-row slabs (measured ~3.7 TB/s).
// Chunk g covers output rows {2g, 2g+1} of one region; lanes 0-31 emit the
// even row, lanes 32-63 the odd row. Index pair fetched as one scalar u64
// load (lgkmcnt — keeps vmcnt free of store-retire chaining); table gathers
// from LDS.
__global__ __launch_bounds__(256) void nif_store_kernel(
    const float* __restrict__ tab, const unsigned* __restrict__ IDX,
    float* __restrict__ out, int B) {
    __shared__ f32x4 TAB[TAB4];                      // 33280 B

    const int tid  = threadIdx.x;
    const int lane = tid & 63;
    const int w    = tid >> 6;                       // wave id 0..3
    const int e4   = lane & 31;                      // float4 column 0..31
    const int lh   = lane >> 5;                      // even/odd row half

    // Stage table into LDS (coalesced).
    const f32x4* __restrict__ tabg = (const f32x4*)tab;
#pragma unroll
    for (int i = 0; i < 8; ++i) TAB[tid + 256 * i] = tabg[tid + 256 * i];
    if (tid < TAB4 - 2048) TAB[2048 + tid] = tabg[2048 + tid];
    __syncthreads();

    const int NSRC = B * (LLEN / 2);     // chunks in the src region (131072)
    const int NCH  = B * LLEN;           // total chunks (262144)
    const int gw     = blockIdx.x * 4 + w;           // wave's first chunk
    const int stride = gridDim.x * 4;                // total waves

    f32x4* __restrict__ out4 = (f32x4*)out;

#pragma unroll 4
    for (int g = gw; g < NCH; g += stride) {
        const bool isdst = (g >= NSRC);
        const int  gc    = isdst ? g - NSRC : g;     // chunk within region
        // rows 2*gc, 2*gc+1 -> adjacent u32s of IDX; one scalar u64 load
        const unsigned row0u = __builtin_amdgcn_readfirstlane(2 * gc);
        const uint2 xx = *(const uint2*)(IDX + row0u);
        const unsigned x = lh ? xx.y : xx.x;
        const int p = isdst ? (int)((x >> 16) & 255) : (int)(x & 255);
        const int q = isdst ? (int)((x >> 24) & 255) : (int)((x >> 8) & 255);
        const f32x4 t = TAB[p * 32 + e4] + TAB[q * 32 + e4];
        out4[(size_t)g * 64 + lane] = t;             // contiguous 1 KiB / wave
    }
}

extern "C" void kernel_launch(void* const* d_in, const int* in_sizes, int n_in,
                              void* d_out, int out_size, void* d_ws, size_t ws_size,
                              hipStream_t stream) {
    const int*   src_id = (const int*)d_in[0];
    const int*   dst_id = (const int*)d_in[1];
    const int*   src_nb = (const int*)d_in[2];
    const int*   dst_nb = (const int*)d_in[3];
    const float* W1     = (const float*)d_in[4];
    const float* b1     = (const float*)d_in[5];
    const float* W2     = (const float*)d_in[6];
    const float* b2     = (const float*)d_in[7];
    float*       out    = (float*)d_out;
    float*       tab    = (float*)d_ws;                          // 33280 B
    unsigned*    IDX    = (unsigned*)((char*)d_ws + 65536);      // 1 MiB

    const int B = in_sizes[0];

    build_table_kernel<<<TMAX, DD, 0, stream>>>(W1, b1, W2, b2, tab);
    build_index_kernel<<<B / 4, 256, 0, stream>>>(
        src_id, dst_id, src_nb, dst_nb, IDX, B);
    // 1024 blocks = 4 blocks/CU (LDS-limited), 16 waves/CU, one moving front.
    nif_store_kernel<<<1024, 256, 0, stream>>>(tab, IDX, out, B);
}

// Round 5
// 278.528 us; speedup vs baseline: 1.0657x; 1.0608x over previous
//
#include <hip/hip_runtime.h>

// B=4096, L=64, D=128, counts in [0,64].
#define DD   128
#define LLEN 64
#define TMAX 65            // table rows: count values 0..64
#define ROWS_PER_BLK 4     // one wave (64 lanes) per batch row
#define TAB4 (TMAX * (DD / 4))   // 2080 float4 elements = 33280 B

// Kernel 1: tab[a][e] = b2[e] + sum_d relu(a*W1[d]+b1[d]) * W2[d][e]
// (b2 folded in: out = tab[A0] + tab[A1] gives ... + 2*b2 as required)
__global__ void build_table_kernel(const float* __restrict__ W1,
                                   const float* __restrict__ b1,
                                   const float* __restrict__ W2,
                                   const float* __restrict__ b2,
                                   float* __restrict__ tab) {
    const int a = blockIdx.x;    // 0..64
    const int e = threadIdx.x;   // 0..127
    const float fa = (float)a;
    float acc = b2[e];
#pragma unroll 8
    for (int d = 0; d < DD; ++d) {
        float h = fmaxf(fmaf(fa, W1[d], b1[d]), 0.f);
        acc = fmaf(h, W2[d * DD + e], acc);
    }
    tab[a * DD + e] = acc;
}

// Kernel 2: 4 batch rows per block, one wave per row. Table staged in LDS.
__global__ __launch_bounds__(256) void nif_main_kernel(
    const int* __restrict__ src_id, const int* __restrict__ dst_id,
    const int* __restrict__ src_nb, const int* __restrict__ dst_nb,
    const float* __restrict__ tab, float* __restrict__ out, int B) {
    __shared__ float4 TAB[TAB4];                      // 33280 B
    __shared__ int S[ROWS_PER_BLK][LLEN], Dn[ROWS_PER_BLK][LLEN];
    __shared__ int A0[ROWS_PER_BLK][LLEN], A1[ROWS_PER_BLK][LLEN];
    __shared__ int C0[ROWS_PER_BLK][LLEN], C1[ROWS_PER_BLK][LLEN];

    const int tid  = threadIdx.x;
    const int w    = tid >> 6;        // wave id 0..3
    const int lane = tid & 63;
    const int b    = blockIdx.x * ROWS_PER_BLK + w;   // this wave's batch row

    // Stage table into LDS (coalesced; 2080 float4 / 256 threads = 8.125 each)
    const float4* __restrict__ tabg = (const float4*)tab;
#pragma unroll
    for (int i = tid; i < TAB4; i += 256) TAB[i] = tabg[i];

    S[w][lane]  = src_nb[(size_t)b * LLEN + lane];
    Dn[w][lane] = dst_nb[(size_t)b * LLEN + lane];
    __syncthreads();

    {
        const int sid = src_id[b];
        const int did = dst_id[b];
        const int vs = S[w][lane];
        const int vd = Dn[w][lane];
        // row scalars via ballot: count of sid in D-row, did in S-row
        const int cd_sid = __popcll(__ballot(vd == sid));
        const int cs_did = __popcll(__ballot(vs == did));
        int c_src = 0, c_dos = 0, c_dst = 0, c_sod = 0;
#pragma unroll 8
        for (int j = 0; j < LLEN; ++j) {
            const int sj = S[w][j], dj = Dn[w][j];
            c_src += (sj == vs);   // count of S[i] in S
            c_dos += (dj == vs);   // count of S[i] in D
            c_dst += (dj == vd);   // count of D[i] in D
            c_sod += (sj == vd);   // count of D[i] in S
        }
        const bool s_in_d = (cd_sid > 0);
        const bool same   = (sid == did);
        const bool c2     = (cs_did > 0) || (same && s_in_d);
        const int  v2     = (same && s_in_d) ? cd_sid : cs_did;
        A0[w][lane] = c_src;                                  // src_app[...,0]
        A1[w][lane] = (vs == did && c2) ? v2 : c_dos;         // src_app[...,1]
        C0[w][lane] = (vd == sid && s_in_d) ? cd_sid : c_sod; // dst_app[...,0]
        C1[w][lane] = c_dst;                                  // dst_app[...,1]
    }
    __syncthreads();

    float4* __restrict__ out4 = (float4*)out;
    const size_t src_base = (size_t)b * (LLEN * DD / 4);            // float4 units
    const size_t dst_base = src_base + (size_t)B * (LLEN * DD / 4);
    const int e4 = lane & 31;   // float4 column 0..31
    const int lh = lane >> 5;   // which of two L-rows this half-wave handles
#pragma unroll 4
    for (int k = 0; k < 32; ++k) {
        const int l = 2 * k + lh;          // L-row 0..63
        const int idx4 = l * 32 + e4;      // contiguous 1KB per wave-iteration
        const float4 t0 = TAB[A0[w][l] * 32 + e4];
        const float4 t1 = TAB[A1[w][l] * 32 + e4];
        float4 v;
        v.x = t0.x + t1.x;
        v.y = t0.y + t1.y;
        v.z = t0.z + t1.z;
        v.w = t0.w + t1.w;
        out4[src_base + idx4] = v;
        const float4 u0 = TAB[C0[w][l] * 32 + e4];
        const float4 u1 = TAB[C1[w][l] * 32 + e4];
        float4 wv;
        wv.x = u0.x + u1.x;
        wv.y = u0.y + u1.y;
        wv.z = u0.z + u1.z;
        wv.w = u0.w + u1.w;
        out4[dst_base + idx4] = wv;
    }
}

extern "C" void kernel_launch(void* const* d_in, const int* in_sizes, int n_in,
                              void* d_out, int out_size, void* d_ws, size_t ws_size,
                              hipStream_t stream) {
    const int*   src_id = (const int*)d_in[0];
    const int*   dst_id = (const int*)d_in[1];
    const int*   src_nb = (const int*)d_in[2];
    const int*   dst_nb = (const int*)d_in[3];
    const float* W1     = (const float*)d_in[4];
    const float* b1     = (const float*)d_in[5];
    const float* W2     = (const float*)d_in[6];
    const float* b2     = (const float*)d_in[7];
    float*       out    = (float*)d_out;
    float*       tab    = (float*)d_ws;   // 65*128 fp32 = 33280 B scratch

    const int B = in_sizes[0];

    build_table_kernel<<<TMAX, DD, 0, stream>>>(W1, b1, W2, b2, tab);
    nif_main_kernel<<<B / ROWS_PER_BLK, 256, 0, stream>>>(
        src_id, dst_id, src_nb, dst_nb, tab, out, B);
}